// Round 6
// baseline (77.522 us; speedup 1.0000x reference)
//
#include <hip/hip_runtime.h>

// DAG reachability closure from node 0 (N=8192, <=2 children, -1 = leaf).
// Reference's N relaxation steps == transitive closure; we BFS to fixpoint.
//
// History: R2 scan/1024t ~21us, R3 scan/256t ~33us, R4 scan/64t ~52us,
// R5 level-sync queue/256t ~24us. Level-sync pays ~2 block barriers + drains
// per BFS level (~30 levels); single-wave pays serial expansion. This round:
// ASYNC work-stealing queue BFS — no barriers in the hot loop at all.
//   - LDS is uncached/coherent per-CU: cross-wave visibility needs only
//     ordering, not __syncthreads.
//   - monotone queue: tail=claim cursor, res=reserved, done=completed.
//     Slots init -1 (sentinel); publisher: reserve -> ds_write node ->
//     __threadfence_block() -> done++. done==res <=> all discovered nodes
//     processed => safe uniform termination (d read before r: if d==r then
//     r is current => truly complete).
//   - worker loop is flat (poll once per iteration, process ready lanes same
//     iteration): no nested per-lane spin => no exec-mask deadlock.
//   - 256 workers (4 waves) bound DS poll pressure; 1024 threads for
//     staging (int4) and output (int4).
// Output: int32 0/1 (harness materializes the bool mask as int32).

#define NMAX  8192
#define BLK   1024
#define NWORK 256

__global__ __launch_bounds__(BLK) void dag_reach_kernel(
    const int* __restrict__ left,
    const int* __restrict__ right,
    int* __restrict__ out,
    int n)
{
    __shared__ int2         sLR[NMAX];          // (left,right) per node, 64 KB
    __shared__ unsigned int visited[NMAX / 32]; // 1 KB bitmask
    __shared__ int          queue[NMAX];        // 32 KB monotone BFS queue
    __shared__ int          s_tail, s_res, s_done;

    const int tid = threadIdx.x;
    const int nv = n / 4;

    // ---- stage edges (int4 loads) + init queue/visited/counters ----
    {
        const int4* l4 = (const int4*)left;
        const int4* r4 = (const int4*)right;
        for (int i = tid; i < nv; i += BLK) {
            int4 l = l4[i];
            int4 r = r4[i];
            int b = i * 4;
            sLR[b + 0] = make_int2(l.x, r.x);
            sLR[b + 1] = make_int2(l.y, r.y);
            sLR[b + 2] = make_int2(l.z, r.z);
            sLR[b + 3] = make_int2(l.w, r.w);
        }
    }
    for (int i = tid; i < NMAX; i += BLK) queue[i] = -1;     // sentinel
    for (int i = tid; i < NMAX / 32; i += BLK) visited[i] = 0u;
    if (tid == 0) { s_tail = 0; s_res = 1; s_done = 0; queue[0] = 0; visited[0] = 1u; }
    __syncthreads();

    // ---- async BFS: 4 worker waves, no barriers ----
    if (tid < NWORK) {
        volatile int* vq    = queue;
        volatile int* vdone = &s_done;
        volatile int* vres  = &s_res;

        int myidx = atomicAdd(&s_tail, 1);   // my claimed slot (unique)
        int node  = -1;

        for (;;) {
            if (node < 0 && myidx < NMAX) node = vq[myidx];  // one poll/iter
            bool ready = (node >= 0);
            if (__any(ready)) {
                if (ready) {
                    int2 lr = sLR[node];
                    if (lr.x >= 0) {
                        unsigned int bit = 1u << (lr.x & 31);
                        unsigned int old = atomicOr(&visited[lr.x >> 5], bit);
                        if (!(old & bit)) {
                            int s = atomicAdd(&s_res, 1);
                            queue[s] = lr.x;                 // publish
                        }
                    }
                    if (lr.y >= 0) {
                        unsigned int bit = 1u << (lr.y & 31);
                        unsigned int old = atomicOr(&visited[lr.y >> 5], bit);
                        if (!(old & bit)) {
                            int s = atomicAdd(&s_res, 1);
                            queue[s] = lr.y;                 // publish
                        }
                    }
                    __threadfence_block();   // pushes land before done++
                    atomicAdd(&s_done, 1);
                    myidx = atomicAdd(&s_tail, 1);           // re-claim
                    node  = -1;
                }
            } else {
                int d = *vdone;              // read done BEFORE res
                int r = *vres;
                if (d == r) break;           // all discovered processed
            }
        }
    }
    __syncthreads();

    // ---- write int32 0/1 mask (int4 stores) ----
    {
        int4* o4 = (int4*)out;
        for (int i = tid; i < nv; i += BLK) {
            unsigned int w = visited[i >> 3];
            int sh = (i & 7) * 4;
            o4[i] = make_int4((int)((w >> (sh + 0)) & 1u),
                              (int)((w >> (sh + 1)) & 1u),
                              (int)((w >> (sh + 2)) & 1u),
                              (int)((w >> (sh + 3)) & 1u));
        }
    }
}

extern "C" void kernel_launch(void* const* d_in, const int* in_sizes, int n_in,
                              void* d_out, int out_size, void* d_ws, size_t ws_size,
                              hipStream_t stream)
{
    // inputs: 0 = thresholds (f32, unused by reference), 1 = left, 2 = right
    const int* left  = (const int*)d_in[1];
    const int* right = (const int*)d_in[2];
    int* out = (int*)d_out;
    const int n = in_sizes[1];

    dag_reach_kernel<<<1, BLK, 0, stream>>>(left, right, out, n);
}

// Round 7
// 72.324 us; speedup vs baseline: 1.0719x; 1.0719x over previous
//
#include <hip/hip_runtime.h>

// DAG reachability closure from node 0 (N=8192, <=2 children, -1 = leaf).
// Reference's N relaxation steps == transitive closure; we iterate to fixpoint.
//
// Kernel-time history (total minus ~50.8us fixed fill/restore overhead):
//   R2 scan/1024t+flags ~21us | R3 scan/256t ~33 | R4 scan/64t ~52
//   R5 level-sync queue/256t ~24 | R6 async queue ~27
// All barriered designs pay (chain ~600-1000cyc + handshake) x ~30 levels.
//
// This round: CHAOTIC Gauss-Seidel + closure-verification rounds.
//   Phase A (no barriers): monotone bit-setting is correct under any
//     schedule. Each of 1024 threads owns 8 nodes (one byte of the mask),
//     polls its word, expands new bits at once via LDS atomicOr (no return
//     needed). Hop = poll interval + ds_read + atomicOr ~ 400cyc vs ~800+
//     for any barriered level. Wave-uniform quiet-exit (__any resets
//     patience) keeps all 64 lanes polling until the whole wave is idle.
//   Phase B (verification = proof): owner re-ors children of every set,
//     unverified bit WITH return check; any newly-set bit => flag => next
//     round. Flag==0 <=> every set bit's children already set <=> closure
//     complete — correctness independent of Phase A timing. Phase B also
//     advances the computation (it's a full Gauss-Seidel step).
// Output: int32 0/1 (harness materializes the bool mask as int32).

#define NMAX 8192
#define BLK  1024

__global__ __launch_bounds__(BLK) void dag_reach_kernel(
    const int* __restrict__ left,
    const int* __restrict__ right,
    int* __restrict__ out,
    int n)
{
    __shared__ int2         sLR[NMAX];          // (left,right) per node, 64 KB
    __shared__ unsigned int visited[NMAX / 32]; // 1 KB bitmask
    __shared__ int          flag[2];            // parity changed-flags

    const int tid = threadIdx.x;
    const int nv  = n / 4;

    // ---- stage edges (int4 loads, int2 LDS) + init ----
    {
        const int4* l4 = (const int4*)left;
        const int4* r4 = (const int4*)right;
        for (int i = tid; i < nv; i += BLK) {
            int4 l = l4[i];
            int4 r = r4[i];
            int b = i * 4;
            sLR[b + 0] = make_int2(l.x, r.x);
            sLR[b + 1] = make_int2(l.y, r.y);
            sLR[b + 2] = make_int2(l.z, r.z);
            sLR[b + 3] = make_int2(l.w, r.w);
        }
    }
    for (int i = tid; i < NMAX / 32; i += BLK) visited[i] = 0u;
    if (tid == 0) { visited[0] = 1u; flag[0] = 0; flag[1] = 0; }
    __syncthreads();

    const int wi   = tid >> 2;          // my word
    const int sh   = (tid & 3) * 8;     // my byte within the word
    const int base = tid * 8;           // my first node
    unsigned int expd = 0u;             // bits I have expanded
    unsigned int verified = 0u;         // bits whose children are proven set
    volatile unsigned int* vvis = visited;

    for (int round = 0; ; ++round) {
        // ---- Phase A: chaotic propagation, zero barriers ----
        {
            const int K = (round == 0) ? 32 : 8;   // patience (quiet polls)
            int quiet = 0;
            while (quiet < K) {
                unsigned int byte = (vvis[wi] >> sh) & 0xFFu;
                unsigned int pend = byte & ~expd;
                if (pend) {
                    expd |= pend;
                    do {
                        int b = __ffs(pend) - 1;
                        pend &= pend - 1;
                        int2 lr = sLR[base + b];
                        if (lr.x >= 0) atomicOr(&visited[lr.x >> 5], 1u << (lr.x & 31));
                        if (lr.y >= 0) atomicOr(&visited[lr.y >> 5], 1u << (lr.y & 31));
                        pend = pend; // keep loop simple
                    } while (pend);
                    quiet = 0;
                } else {
                    quiet = __any(0) ? 0 : quiet + 1;  // uniform: no lane had pend
                }
                // wave-uniform patience: any lane's activity resets the wave
                if (__any((vvis[wi] >> sh) & ~expd & 0xFFu)) quiet = 0;
            }
        }
        __syncthreads();   // all pushes visible; no one writes during Phase B reads

        // ---- Phase B: verification sweep (Gauss-Seidel with detection) ----
        bool bad = false;
        {
            unsigned int byte = (visited[wi] >> sh) & 0xFFu;
            expd |= byte;                          // fold in anything unseen
            unsigned int chk = expd & ~verified;   // set bits not yet proven
            while (chk) {
                int b = __ffs(chk) - 1;
                chk &= chk - 1;
                int2 lr = sLR[base + b];
                if (lr.x >= 0) {
                    unsigned int bit = 1u << (lr.x & 31);
                    unsigned int old = atomicOr(&visited[lr.x >> 5], bit);
                    if (!(old & bit)) bad = true;  // discovered a new node
                }
                if (lr.y >= 0) {
                    unsigned int bit = 1u << (lr.y & 31);
                    unsigned int old = atomicOr(&visited[lr.y >> 5], bit);
                    if (!(old & bit)) bad = true;
                }
            }
            verified = expd;
        }
        if (bad)      flag[round & 1] = 1;         // benign same-value race
        if (tid == 0) flag[(round + 1) & 1] = 0;   // pre-reset next parity
        __syncthreads();                           // B1: flag set visible
        int f = flag[round & 1];
        __syncthreads();                           // B2: protect from next reset
        if (!f) break;                             // closed => done
    }

    // ---- write int32 0/1 mask (int4 stores) ----
    {
        int4* o4 = (int4*)out;
        for (int i = tid; i < nv; i += BLK) {
            unsigned int w = visited[i >> 3];
            int s = (i & 7) * 4;
            o4[i] = make_int4((int)((w >> (s + 0)) & 1u),
                              (int)((w >> (s + 1)) & 1u),
                              (int)((w >> (s + 2)) & 1u),
                              (int)((w >> (s + 3)) & 1u));
        }
    }
}

extern "C" void kernel_launch(void* const* d_in, const int* in_sizes, int n_in,
                              void* d_out, int out_size, void* d_ws, size_t ws_size,
                              hipStream_t stream)
{
    // inputs: 0 = thresholds (f32, unused by reference), 1 = left, 2 = right
    const int* left  = (const int*)d_in[1];
    const int* right = (const int*)d_in[2];
    int* out = (int*)d_out;
    const int n = in_sizes[1];

    dag_reach_kernel<<<1, BLK, 0, stream>>>(left, right, out, n);
}